// Round 2
// baseline (232.012 us; speedup 1.0000x reference)
//
#include <hip/hip_runtime.h>

// FRFT with diagonal transform matrices (Evec = I in the reference):
//   out[n,c,h,w] = D[(h+128)%256] * D[(w+128)%256] * x[n,c,h,w]
// where D[i] = 16 * exp(-i * (pi/2) * a * l_i),  l_i = i (i<255), l_255 = 256.
// Pure memory-bound elementwise complex scale. Output complex64 ->
// interleaved (re, im) float32 pairs.
//
// Round-2 established: every memory instruction unit-stride dense across the
// wave (float2 load = 8 B/lane, float4 store = 16 B/lane). Keep that.
//
// Round-3 changes:
//  1. Block-strided K-loop: each thread handles KIT=8 float2 vectors at
//     p = base + k*256 + t, so every load/store instruction is still a dense
//     unit-stride wavefront access, but the per-thread double-sincos table
//     build + __syncthreads amortizes over 16 elements instead of 2
//     (16.7M -> 2.1M double sincos total).
//  2. Table stored as float2 (cos,sin) pairs, 16B-aligned. Since w0 is always
//     even, (c0,s0,c1,s1) is one ds_read_b128; (ch,sh) is one wave-uniform
//     ds_read_b64 broadcast. 6 scalar LDS reads -> 2 vector LDS reads.
//  3. Non-temporal stores: output is write-once streaming (268 MB); keep it
//     out of L2/L3 so the 134 MB input can stay L3-resident across replays.
//     NOTE: __builtin_nontemporal_store requires a NATIVE vector type —
//     HIP float4 (HIP_vector_type class) is rejected; use ext_vector_type.

typedef float f32x2 __attribute__((ext_vector_type(2)));
typedef float f32x4 __attribute__((ext_vector_type(4)));

constexpr int HW    = 256;  // H == W == 256
constexpr int BLOCK = 256;
constexpr int KIT   = 8;    // float2 vectors per thread

__global__ __launch_bounds__(BLOCK) void frft_diag_kernel(
    const float* __restrict__ x,
    const float* __restrict__ order,
    float* __restrict__ out,
    int interleaved,
    int nvec2)   // number of float2 input vectors = total/2
{
    // Shifted diagonal table: entry i = 16 * (cos, sin) of theta for index
    // (i+128)%256. 16B-aligned so a float4 read at even i is legal.
    __shared__ alignas(16) f32x2 tbl[HW];

    const int t = threadIdx.x;
    // Build once per block (256 threads -> 256 entries). Double precision:
    // phase reaches ~2400 rad; double sincos keeps argument-reduction error
    // negligible vs the 2% threshold.
    {
        const int idx = t ^ 128;                       // (t + 128) % 256
        const double l = (idx == 255) ? 256.0 : (double)idx;
        const double theta = 1.5707963267948966 * (double)order[0] * l;
        double s, c;
        sincos(theta, &s, &c);
        tbl[t] = (f32x2){(float)(16.0 * c), (float)(16.0 * s)};
    }
    __syncthreads();

    const int base = blockIdx.x * (BLOCK * KIT) + t;

#pragma unroll
    for (int k = 0; k < KIT; ++k) {
        const int p = base + k * BLOCK;                // float2 index
        if (p >= nvec2) continue;                      // nvec2 % 2048 == 0 in practice

        const f32x2 xv = ((const f32x2*)x)[p];
        const int w0 = (p & 127) << 1;                 // even, in [0, 254]
        const int h  = (p >> 7) & (HW - 1);            // wave-uniform -> broadcast

        const f32x2 th = tbl[h];                                           // ds_read_b64
        const f32x4 tw = *reinterpret_cast<const f32x4*>(&tbl[w0]);        // ds_read_b128
        // tw = (c0, s0, c1, s1)

        // (ch - i*sh)(cw - i*sw) = (ch*cw - sh*sw) - i(ch*sw + sh*cw)
        const float pr0 = th.x * tw.x - th.y * tw.y;
        const float pi0 = th.x * tw.y + th.y * tw.x;
        const float pr1 = th.x * tw.z - th.y * tw.w;
        const float pi1 = th.x * tw.w + th.y * tw.z;

        if (interleaved) {
            f32x4 o = { xv.x * pr0, -xv.x * pi0, xv.y * pr1, -xv.y * pi1 };
            __builtin_nontemporal_store(o, &((f32x4*)out)[p]);
        } else {
            f32x2 o = { xv.x * pr0, xv.y * pr1 };
            __builtin_nontemporal_store(o, &((f32x2*)out)[p]);
        }
    }
}

extern "C" void kernel_launch(void* const* d_in, const int* in_sizes, int n_in,
                              void* d_out, int out_size, void* d_ws, size_t ws_size,
                              hipStream_t stream) {
    const float* x     = (const float*)d_in[0];
    const float* order = (const float*)d_in[1];
    float* out = (float*)d_out;

    const int total = in_sizes[0];
    const int nvec2 = total / 2;            // float2 vectors
    const int interleaved = (out_size >= 2 * total) ? 1 : 0;

    const int per_block = BLOCK * KIT;      // 2048 float2 per block
    const int grid = (nvec2 + per_block - 1) / per_block;
    frft_diag_kernel<<<grid, BLOCK, 0, stream>>>(x, order, out, interleaved, nvec2);
}